// Round 11
// baseline (2586.984 us; speedup 1.0000x reference)
//
#include <hip/hip_runtime.h>

#define NPLANES 24
#define IMG 192
#define RW 194        // f16 ring stride in halfs; ring col = 3 + delta-col (pads zero)
#define TSTEPS 926    // wavefront t = 4*i + j

typedef _Float16 h2v   __attribute__((ext_vector_type(2)));
typedef _Float16 f16x8 __attribute__((ext_vector_type(8)));
typedef float    f32x4 __attribute__((ext_vector_type(4)));
typedef __fp16   fp16x2 __attribute__((ext_vector_type(2)));

__device__ __forceinline__ h2v pk(float a, float b) {
  union { fp16x2 p; h2v h; } u;
  u.p = __builtin_amdgcn_cvt_pkrtz(a, b);
  return u.h;
}
__device__ __forceinline__ float fast_tanh(float x) {
  float e = __expf(2.0f * x);
  return 1.0f - 2.0f / (e + 1.0f);
}

// One block per plane, 192 threads = 3 waves, point-to-point sync.
// Wave w owns cells 16w..16w+15 (slot = row i mod 48). Per cell, the 21 delta
// taps slide in quad0-lane REGISTERS: new entries are 2 stale ring reads
// (prefetched one step early) + the neighbor lane's fresh delta via shfl_up
// (LDS mailbox at wave boundaries). The cross-wave spin gates ONLY the mailbox;
// A-fragments and the K<32 half of L1 issue pre-spin.
__launch_bounds__(192)
__global__ void codec_kernel(const float* __restrict__ x,
                             const float* __restrict__ W1g, const float* __restrict__ b1g,
                             const float* __restrict__ W2g, const float* __restrict__ b2g,
                             const float* __restrict__ W3g, const float* __restrict__ b3g,
                             const float* __restrict__ W4g, const float* __restrict__ b4g,
                             float* __restrict__ ws)
{
  __shared__ _Float16 ringH[64 * RW];   // f16 deltas; cols 0..2 & >=189 stay 0
  __shared__ _Float16 featA[48 * 72];   // [cell][48 feat | 16 ZERO K-pad | 8 pad]
  __shared__ _Float16 h1A  [48 * 104];
  __shared__ _Float16 h2A  [48 * 40];
  __shared__ _Float16 w1B  [96 * 72];
  __shared__ _Float16 w2B  [32 * 104];
  __shared__ _Float16 w3B  [16 * 32];
  __shared__ _Float16 mboxL[4 * 4];     // [wave][t&3] fresh boundary delta
  __shared__ float    b1L[96], b2L[24], b3L[16], w4F[16], b4L[1];
  __shared__ int      ctrL[4];
  __shared__ float    wsum[3];

  const int tid  = threadIdx.x;
  const int lane = tid & 63;
  const int w    = __builtin_amdgcn_readfirstlane(tid >> 6);
  const int lam  = lane & 15;
  const int quad = lane >> 4;
  const int cell = 16 * w + lam;
  const float* __restrict__ xp = x + (size_t)blockIdx.x * (IMG * IMG);

  // ---- one-time init ----
  { unsigned* z = (unsigned*)ringH; for (int u = tid; u < 64 * RW / 2;  u += 192) z[u] = 0; }
  { unsigned* z = (unsigned*)featA; for (int u = tid; u < 48 * 72 / 2;  u += 192) z[u] = 0; }
  { unsigned* z = (unsigned*)h1A;   for (int u = tid; u < 48 * 104 / 2; u += 192) z[u] = 0; }
  { unsigned* z = (unsigned*)h2A;   for (int u = tid; u < 48 * 40 / 2;  u += 192) z[u] = 0; }
  for (int u = tid; u < 96 * 72; u += 192) {
    int n = u / 72, k = u - n * 72;
    w1B[u] = (k < 48) ? (_Float16)W1g[k * 96 + n] : (_Float16)0.f;
  }
  for (int u = tid; u < 32 * 104; u += 192) {
    int n = u / 104, k = u - n * 104;
    w2B[u] = (n < 24 && k < 96) ? (_Float16)W2g[k * 24 + n] : (_Float16)0.f;
  }
  for (int u = tid; u < 16 * 32; u += 192) {
    int n = u / 32, k = u - n * 32;
    w3B[u] = (n < 12 && k < 24) ? (_Float16)W3g[k * 12 + n] : (_Float16)0.f;
  }
  for (int u = tid; u < 96; u += 192) b1L[u] = b1g[u];
  if (tid < 24) b2L[tid] = b2g[tid];
  if (tid < 16) b3L[tid] = (tid < 12) ? b3g[tid] : 0.f;
  if (tid < 16) w4F[tid] = (tid < 12) ? W4g[tid] : 0.f;
  if (tid == 0) b4L[0] = b4g[0];
  if (tid < 16) mboxL[tid] = (_Float16)0.f;
  if (tid < 4)  ctrL[tid] = -1;
  __syncthreads();

  // ---- persistent MFMA weight fragments ----
  f16x8 B1[6][2], B2[2][3], B3;
  float bias1v[6], bias2v[2];
  #pragma unroll
  for (int nt = 0; nt < 6; ++nt) {
    #pragma unroll
    for (int kt = 0; kt < 2; ++kt)
      B1[nt][kt] = *(const f16x8*)&w1B[(16 * nt + lam) * 72 + quad * 8 + 32 * kt];
    bias1v[nt] = b1L[16 * nt + lam];
  }
  #pragma unroll
  for (int nt = 0; nt < 2; ++nt) {
    #pragma unroll
    for (int kt = 0; kt < 3; ++kt)
      B2[nt][kt] = *(const f16x8*)&w2B[(16 * nt + lam) * 104 + quad * 8 + 32 * kt];
    bias2v[nt] = (16 * nt + lam < 24) ? b2L[16 * nt + lam] : 0.f;
  }
  B3 = *(const f16x8*)&w3B[lam * 32 + quad * 8];
  const float bias3v = b3L[lam];
  const float w4v    = w4F[lam];
  const float b4v    = b4L[0];

  // quad0 per-lane sliding state
  float xw[3][7], xl3[3], xt = 0.f;
  float px0 = 0.f, px1 = 0.f, px2 = 0.f, px3 = 0.f;
  float tr[3][7] = {{0}};               // delta taps, rows i-3..i-1, padded cols j..j+6
  float pr2 = 0.f, pr3 = 0.f;           // prefetched next-step entries (rows i-2, i-3)
  float dl1 = 0.f, dl2 = 0.f, dl3 = 0.f;
  bool  wp = false;
  float sumsq = 0.0f;
  const int prodw = (w == 0) ? 2 : w - 1;

  for (int t = 0; t < TSTEPS; ++t) {
    const int i_min = (t <= 185) ? 0 : ((t - 182) >> 2);
    int i_max = t >> 2; if (i_max > 185) i_max = 185;
    const int k48 = (i_min - cell + 47) / 48;
    const int i = cell + 48 * k48;
    const bool active = (i <= i_max);
    const int j = t - 4 * i;

    // fresh neighbor delta (row i-1, col j+3) from lam-1's register
    const float ndlv = __shfl_up(dl1, 1, 64);
    const float ndl = (active && j <= 182) ? ndlv : 0.f;   // lam0: fixed post-spin

    // ---- pre-spin: build features (quad0) ----
    if (quad == 0) {
      if (active) {
        if (j == 0) {
          if (!wp) {                         // only t==0 cell 0
            const float* xr = xp + i * IMG;
            #pragma unroll
            for (int r = 0; r < 3; ++r)
              #pragma unroll
              for (int c = 0; c < 7; ++c) xw[r][c] = xr[r * IMG + c];
            #pragma unroll
            for (int c = 0; c < 3; ++c) xl3[c] = xr[3 * IMG + c];
            xt = xr[3 * IMG + 3];
          }
          wp = false;
          dl1 = dl2 = dl3 = 0.f;
          // cold tap load (all entries >= t-2 old; row i-1 col 3 arrives as ndl)
          const int r0 = ((i - 3) & 63) * RW;
          const int r1 = ((i - 2) & 63) * RW;
          const int r2 = ((i - 1) & 63) * RW;
          #pragma unroll
          for (int c = 0; c < 7; ++c) tr[0][c] = (float)ringH[r0 + c];
          #pragma unroll
          for (int c = 0; c < 7; ++c) tr[1][c] = (float)ringH[r1 + c];
          #pragma unroll
          for (int c = 0; c < 6; ++c) tr[2][c] = (float)ringH[r2 + c];
        } else {
          #pragma unroll
          for (int r = 0; r < 3; ++r) {
            #pragma unroll
            for (int c = 0; c < 6; ++c) xw[r][c] = xw[r][c + 1];
          }
          xw[0][6] = px0; xw[1][6] = px1; xw[2][6] = px2;
          xl3[0] = xl3[1]; xl3[1] = xl3[2]; xl3[2] = xt;
          xt = px3;
          #pragma unroll
          for (int r = 0; r < 3; ++r)
            #pragma unroll
            for (int c = 0; c < 6; ++c) tr[r][c] = tr[r][c + 1];
          tr[0][6] = pr3; tr[1][6] = pr2;
        }
        tr[2][6] = ndl;

        float fx[48];
        #pragma unroll
        for (int r = 0; r < 3; ++r)
          #pragma unroll
          for (int c = 0; c < 7; ++c) fx[7 * r + c] = xw[r][c];
        fx[21] = xl3[0]; fx[22] = xl3[1]; fx[23] = xl3[2];
        #pragma unroll
        for (int r = 0; r < 3; ++r)
          #pragma unroll
          for (int c = 0; c < 7; ++c) fx[24 + 7 * r + c] = tr[r][c];
        fx[45] = dl3; fx[46] = dl2; fx[47] = dl1;

        union { h2v p[24]; float4 v[6]; } fb;
        #pragma unroll
        for (int q = 0; q < 24; ++q) fb.p[q] = pk(fx[2 * q], fx[2 * q + 1]);
        #pragma unroll
        for (int q = 0; q < 6; ++q)
          *(float4*)&featA[cell * 72 + 8 * q] = fb.v[q];

        // prefetch next-step entries (stale data, off-chain)
        if (j < 185) {
          const float* xr = xp + i * IMG + j;
          px0 = xr[7]; px1 = xr[IMG + 7]; px2 = xr[2 * IMG + 7]; px3 = xr[3 * IMG + 4];
          pr3 = (float)ringH[((i - 3) & 63) * RW + j + 7];
          pr2 = (float)ringH[((i - 2) & 63) * RW + j + 7];
        }
      } else if (j == -1 && i <= 185) {    // cold-start prefetch for next row
        const float* xr = xp + i * IMG;
        #pragma unroll
        for (int r = 0; r < 3; ++r)
          #pragma unroll
          for (int c = 0; c < 7; ++c) xw[r][c] = xr[r * IMG + c];
        #pragma unroll
        for (int c = 0; c < 3; ++c) xl3[c] = xr[3 * IMG + c];
        xt = xr[3 * IMG + 3];
        wp = true;
      }
    }

    // ---- pre-spin: A-frags + first K-half of L1 (all data >= 2 steps old) ----
    f16x8 A1a = *(const f16x8*)&featA[cell * 72 + quad * 8];
    f16x8 A1b = *(const f16x8*)&featA[cell * 72 + quad * 8 + 32];
    f32x4 acc[6];
    #pragma unroll
    for (int nt = 0; nt < 6; ++nt) {
      acc[nt] = (f32x4){bias1v[nt], bias1v[nt], bias1v[nt], bias1v[nt]};
      acc[nt] = __builtin_amdgcn_mfma_f32_16x16x32_f16(A1a, B1[nt][0], acc[nt], 0, 0, 0);
    }

    // ---- spin: gates ONLY the boundary mailbox value ----
    if (t > 0) {
      while (__hip_atomic_load(&ctrL[prodw], __ATOMIC_ACQUIRE,
                               __HIP_MEMORY_SCOPE_WORKGROUP) < t - 1) { }
    }
    if (lam == 0) {
      float mval = 0.f;
      if (t > 0 && active && i >= 1 && j <= 182)
        mval = (float)mboxL[prodw * 4 + ((t - 1) & 3)];
      if (quad == 0) tr[2][6] = mval;                 // for next step's slide
      if (quad == 1) A1b[4] = (_Float16)mval;         // k=44 of cell 16w (lane 16)
    }

    // ---- L1 second half + tanh + h1 stores ----
    #pragma unroll
    for (int nt = 0; nt < 6; ++nt) {
      acc[nt] = __builtin_amdgcn_mfma_f32_16x16x32_f16(A1b, B1[nt][1], acc[nt], 0, 0, 0);
      #pragma unroll
      for (int r = 0; r < 4; ++r)
        h1A[(16 * w + quad * 4 + r) * 104 + 16 * nt + lam] = (_Float16)fast_tanh(acc[nt][r]);
    }

    // ---- L2: K=96, 3 independent MFMAs per n-tile ----
    {
      f16x8 A2[3];
      #pragma unroll
      for (int kt = 0; kt < 3; ++kt)
        A2[kt] = *(const f16x8*)&h1A[cell * 104 + quad * 8 + 32 * kt];
      #pragma unroll
      for (int nt = 0; nt < 2; ++nt) {
        f32x4 za = {bias2v[nt], bias2v[nt], bias2v[nt], bias2v[nt]};
        f32x4 zb = {0.f, 0.f, 0.f, 0.f};
        f32x4 zc = {0.f, 0.f, 0.f, 0.f};
        za = __builtin_amdgcn_mfma_f32_16x16x32_f16(A2[0], B2[nt][0], za, 0, 0, 0);
        zb = __builtin_amdgcn_mfma_f32_16x16x32_f16(A2[1], B2[nt][1], zb, 0, 0, 0);
        zc = __builtin_amdgcn_mfma_f32_16x16x32_f16(A2[2], B2[nt][2], zc, 0, 0, 0);
        const int n = 16 * nt + lam;
        if (n < 24) {
          #pragma unroll
          for (int r = 0; r < 4; ++r)
            h2A[(16 * w + quad * 4 + r) * 40 + n] =
                (_Float16)fast_tanh(za[r] + zb[r] + zc[r]);
        }
      }
    }

    // ---- L3 (1 MFMA) + L4 butterfly ----
    float psum;
    {
      const f16x8 A3 = *(const f16x8*)&h2A[cell * 40 + quad * 8];
      f32x4 a3 = {bias3v, bias3v, bias3v, bias3v};
      a3 = __builtin_amdgcn_mfma_f32_16x16x32_f16(A3, B3, a3, 0, 0, 0);
      f32x4 vv;
      #pragma unroll
      for (int r = 0; r < 4; ++r) vv[r] = fast_tanh(a3[r]) * w4v;   // w4v=0 pads
      #pragma unroll
      for (int mask = 1; mask < 16; mask <<= 1) {
        #pragma unroll
        for (int r = 0; r < 4; ++r) vv[r] += __shfl_xor(vv[r], mask, 64);
      }
      const float selLo = (lam & 1) ? vv[1] : vv[0];
      const float selHi = (lam & 1) ? vv[3] : vv[2];
      const float sel   = (lam & 2) ? selHi : selLo;
      const int src = ((lam >> 2) << 4) | (lam & 3);
      psum = __shfl(sel, src, 64);
    }

    // ---- finalize (quad0) ----
    if (quad == 0 && active) {
      const float pred = fast_tanh(psum + b4v);
      const float d = xt - pred;
      ringH[(i & 63) * RW + 3 + j] = (_Float16)d;
      dl3 = dl2; dl2 = dl1; dl1 = d;
      sumsq += d * d;
    }
    if (lane == 15) mboxL[w * 4 + (t & 3)] = (_Float16)dl1;   // boundary delta
    if (lane == 0)
      __hip_atomic_store(&ctrL[w], t, __ATOMIC_RELEASE, __HIP_MEMORY_SCOPE_WORKGROUP);
  }

  #pragma unroll
  for (int off = 32; off >= 1; off >>= 1)
    sumsq += __shfl_down(sumsq, off);
  if (lane == 0) wsum[w] = sumsq;
  __syncthreads();
  if (tid == 0) ws[blockIdx.x] = wsum[0] + wsum[1] + wsum[2];
}

__global__ void finalize_kernel(const float* __restrict__ ws, float* __restrict__ out) {
  if (threadIdx.x == 0) {
    float s = 0.0f;
    #pragma unroll
    for (int p = 0; p < NPLANES; ++p) s += ws[p];
    out[0] = sqrtf(s / 875520.0f);   // b*c*(h-2)*w = 8*3*190*192
  }
}

extern "C" void kernel_launch(void* const* d_in, const int* in_sizes, int n_in,
                              void* d_out, int out_size, void* d_ws, size_t ws_size,
                              hipStream_t stream) {
  (void)in_sizes; (void)n_in; (void)out_size; (void)ws_size;
  const float* x  = (const float*)d_in[0];
  const float* W1 = (const float*)d_in[1];
  const float* b1 = (const float*)d_in[2];
  const float* W2 = (const float*)d_in[3];
  const float* b2 = (const float*)d_in[4];
  const float* W3 = (const float*)d_in[5];
  const float* b3 = (const float*)d_in[6];
  const float* W4 = (const float*)d_in[7];
  const float* b4 = (const float*)d_in[8];
  float* ws = (float*)d_ws;

  codec_kernel<<<NPLANES, 192, 0, stream>>>(x, W1, b1, W2, b2, W3, b3, W4, b4, ws);
  finalize_kernel<<<1, 64, 0, stream>>>(ws, (float*)d_out);
}